// Round 1
// baseline (322.154 us; speedup 1.0000x reference)
//
#include <hip/hip_runtime.h>
#include <hip/hip_bf16.h>

// Problem constants (B,T,H fixed by setup_inputs)
#define B_ 16
#define T_ 8192
#define H_ 256
#define M_ (B_ * T_)   // 131072 rows
#define K_ 512         // concatenated K: [x | means]
#define STRIDE_ 8      // window over [max(0,t-8), t], count = min(t+1, 9)

typedef __bf16 bf16x8 __attribute__((ext_vector_type(8)));
typedef float f32x4 __attribute__((ext_vector_type(4)));

// round-to-nearest-even fp32 -> bf16 bits (manual, avoids API ambiguity)
__device__ __forceinline__ unsigned short f2bf(float f) {
  unsigned u = __builtin_bit_cast(unsigned, f);
  u += 0x7fffu + ((u >> 16) & 1u);
  return (unsigned short)(u >> 16);
}

// async global -> LDS, 16 bytes per lane (global_load_lds_dwordx4)
__device__ __forceinline__ void load_lds16(const void* g, void* l) {
  __builtin_amdgcn_global_load_lds(
      (const __attribute__((address_space(1))) void*)g,
      (__attribute__((address_space(3))) void*)l, 16, 0, 0);
}

// ---------------------------------------------------------------------------
// Kernel 1: pack Wcat[o][k] = k<256 ? W_lin[o][k] : W_mem[o][k-256]  (bf16)
//           and bias[o] = b_lin[o] + b_mem[o]
// grid: 512 x 256 threads (131072 elements)
// ---------------------------------------------------------------------------
__global__ __launch_bounds__(256) void wcat_kernel(
    const float* __restrict__ Wl, const float* __restrict__ bl,
    const float* __restrict__ Wm, const float* __restrict__ bm,
    unsigned short* __restrict__ Wcat, float* __restrict__ bias) {
  const int e = blockIdx.x * 256 + threadIdx.x;
  const int o = e >> 9;
  const int k = e & 511;
  const float w = (k < 256) ? Wl[o * 256 + k] : Wm[o * 256 + (k - 256)];
  Wcat[e] = f2bf(w);
  if (e < 256) bias[e] = bl[e] + bm[e];
}

// ---------------------------------------------------------------------------
// Kernel 2: build A_cat [M, 512] bf16: cols 0..255 = bf16(x), 256..511 = means
// Each block: 64 tokens of one batch. Thread: column-pair p (float2), 32 rows.
// Running window sum over ring of 9 (zero-padded below batch start).
// grid: 2048 x 256 threads
// ---------------------------------------------------------------------------
__global__ __launch_bounds__(256) void prep_kernel(const float* __restrict__ x,
                                                   unsigned* __restrict__ Acat) {
  const int blk = blockIdx.x;
  const int b = blk >> 7;            // 128 tiles per batch (8192/64)
  const int t0 = (blk & 127) << 6;   // 64 rows per block
  const int g = threadIdx.x >> 7;    // row-group 0/1 (32 rows each)
  const int p = threadIdx.x & 127;   // float2 column pair (256 cols)
  const int tbase = t0 + (g << 5);
  const float2* __restrict__ x2 = (const float2*)x;
  const size_t rb = (size_t)b * T_;

  float vx[40], vy[40];
#pragma unroll
  for (int i = 0; i < 40; ++i) {
    const int t = tbase - 8 + i;     // 8-row halo (uniform branch, only tile 0)
    float xx = 0.f, yy = 0.f;
    if (t >= 0) {
      const float2 val = x2[(rb + t) * 128 + p];
      xx = val.x; yy = val.y;
    }
    vx[i] = xx; vy[i] = yy;
  }
  float sx = 0.f, sy = 0.f;
#pragma unroll
  for (int i = 0; i < 8; ++i) { sx += vx[i]; sy += vy[i]; }
#pragma unroll
  for (int r = 0; r < 32; ++r) {
    const int t = tbase + r;
    sx += vx[r + 8]; sy += vy[r + 8];
    const float cnt = (t >= STRIDE_) ? 9.f : (float)(t + 1);
    const float inv = __builtin_amdgcn_rcpf(cnt);  // bf16 rounding swamps rcp err
    const unsigned xpack =
        (unsigned)f2bf(vx[r + 8]) | ((unsigned)f2bf(vy[r + 8]) << 16);
    const unsigned mpack =
        (unsigned)f2bf(sx * inv) | ((unsigned)f2bf(sy * inv) << 16);
    const size_t row = rb + t;
    Acat[row * 256 + p] = xpack;        // x part: pairs 0..127
    Acat[row * 256 + 128 + p] = mpack;  // means part: pairs 128..255
    sx -= vx[r]; sy -= vy[r];
  }
}

// ---------------------------------------------------------------------------
// Kernel 3: C[M,256] = A_cat[M,512] @ Wcat[256,512]^T + bias   (bf16 MFMA)
// 128x128 block tile, 4 waves in 2x2, each wave 64x64 = 4x4 frags 16x16x32.
// BK=32, global_load_lds width-16 staging (m97 structure).
// grid: (1024, 2) x 256 threads
// ---------------------------------------------------------------------------
__global__ __launch_bounds__(256) void gemm_kernel(
    const unsigned short* __restrict__ A,   // [M, 512] bf16 bits
    const unsigned short* __restrict__ Wc,  // [256, 512] bf16 bits (B^T)
    const float* __restrict__ bias,         // [256]
    float* __restrict__ out) {              // [M, 256] fp32
  __shared__ __align__(16) unsigned short As[128 * 32];
  __shared__ __align__(16) unsigned short Bs[128 * 32];
  const int tid = threadIdx.x;
  const int m0 = blockIdx.x << 7;
  const int n0 = blockIdx.y << 7;
  const int w = tid >> 6;
  const int l = tid & 63;
  const int wr = (w >> 1) << 6;  // wave M offset
  const int wc = (w & 1) << 6;   // wave N offset
  const int lm = l & 15;         // row within 16 (A: m, B: n, C: col)
  const int kq = (l >> 4) << 3;  // k offset within 32

  // staging chunk ids: 16B chunks; chunk f -> row f/4, col (f%4)*8
  const int f0 = tid, f1 = tid + 256;
  const size_t ga0 = (size_t)(m0 + (f0 >> 2)) * 512 + ((f0 & 3) << 3);
  const size_t ga1 = (size_t)(m0 + (f1 >> 2)) * 512 + ((f1 & 3) << 3);
  const size_t gb0 = (size_t)(n0 + (f0 >> 2)) * 512 + ((f0 & 3) << 3);
  const size_t gb1 = (size_t)(n0 + (f1 >> 2)) * 512 + ((f1 & 3) << 3);

  f32x4 acc[4][4];
#pragma unroll
  for (int i = 0; i < 4; ++i)
#pragma unroll
    for (int j = 0; j < 4; ++j) acc[i][j] = (f32x4){0.f, 0.f, 0.f, 0.f};

  for (int k0 = 0; k0 < K_; k0 += 32) {
    __syncthreads();  // previous iter's ds_reads done before overwrite
    load_lds16(A + ga0 + k0, &As[f0 * 8]);
    load_lds16(A + ga1 + k0, &As[f1 * 8]);
    load_lds16(Wc + gb0 + k0, &Bs[f0 * 8]);
    load_lds16(Wc + gb1 + k0, &Bs[f1 * 8]);
    __syncthreads();  // vmcnt drained at barrier -> LDS valid

    bf16x8 a[4], bb[4];
#pragma unroll
    for (int i = 0; i < 4; ++i)
      a[i] = *(const bf16x8*)&As[(wr + i * 16 + lm) * 32 + kq];
#pragma unroll
    for (int j = 0; j < 4; ++j)
      bb[j] = *(const bf16x8*)&Bs[(wc + j * 16 + lm) * 32 + kq];
#pragma unroll
    for (int i = 0; i < 4; ++i)
#pragma unroll
      for (int j = 0; j < 4; ++j)
        acc[i][j] =
            __builtin_amdgcn_mfma_f32_16x16x32_bf16(a[i], bb[j], acc[i][j], 0, 0, 0);
  }

  // epilogue: C/D layout col = l&15, row = (l>>4)*4 + reg
  const int r0 = (l >> 4) << 2;
#pragma unroll
  for (int j = 0; j < 4; ++j) {
    const int o = n0 + wc + j * 16 + lm;
    const float bs = bias[o];
#pragma unroll
    for (int i = 0; i < 4; ++i) {
      const size_t mr = (size_t)(m0 + wr + i * 16 + r0);
#pragma unroll
      for (int r = 0; r < 4; ++r) out[(mr + r) * 256 + o] = acc[i][j][r] + bs;
    }
  }
}

// ---------------------------------------------------------------------------
extern "C" void kernel_launch(void* const* d_in, const int* in_sizes, int n_in,
                              void* d_out, int out_size, void* d_ws, size_t ws_size,
                              hipStream_t stream) {
  const float* x  = (const float*)d_in[0];
  const float* Wl = (const float*)d_in[1];
  const float* bl = (const float*)d_in[2];
  const float* Wm = (const float*)d_in[3];
  const float* bm = (const float*)d_in[4];
  float* out = (float*)d_out;

  // workspace layout (needs ~128.25 MiB):
  //   Acat  [M_*K_] bf16 = 134217728 B
  //   Wcat  [256*512] bf16 = 262144 B
  //   bias  [256] f32 = 1024 B
  char* ws = (char*)d_ws;
  unsigned* Acat = (unsigned*)ws;
  unsigned short* Wcat = (unsigned short*)(ws + (size_t)M_ * K_ * 2);
  float* bias = (float*)(ws + (size_t)M_ * K_ * 2 + (size_t)256 * 512 * 2);

  wcat_kernel<<<512, 256, 0, stream>>>(Wl, bl, Wm, bm, Wcat, bias);
  prep_kernel<<<2048, 256, 0, stream>>>(x, Acat);
  gemm_kernel<<<dim3(M_ / 128, 2), 256, 0, stream>>>(
      (const unsigned short*)Acat, Wcat, bias, out);
}